// Round 10
// baseline (275.244 us; speedup 1.0000x reference)
//
#include <hip/hip_runtime.h>
#include <stdint.h>

#define BB 4
#define TT 2048
#define DD 1024

typedef unsigned short u16;
typedef unsigned int u32;
typedef u16 u16x4 __attribute__((ext_vector_type(4)));
typedef u16 u16x8 __attribute__((ext_vector_type(8)));
typedef float f32x4 __attribute__((ext_vector_type(4)));
typedef short s16x8 __attribute__((ext_vector_type(8)));

__device__ __forceinline__ u16 f2bf(float f) {
  u32 u = __float_as_uint(f);
  return (u16)((u + 0x7fffu + ((u >> 16) & 1u)) >> 16);
}
__device__ __forceinline__ float bf2f(u16 h) {
  return __uint_as_float((u32)h << 16);
}

__device__ __forceinline__ void gload_lds16(const void* g, void* l) {
  __builtin_amdgcn_global_load_lds(
      (const __attribute__((address_space(1))) u32*)g,
      (__attribute__((address_space(3))) u32*)l, 16, 0, 0);
}

// XCD-aware block swizzle (bijection; needs gridM%4==0, gridN%2==0).
__device__ __forceinline__ void swz(int BMv, int BNv, int& tileM, int& tileN) {
  const int gN = gridDim.x, gM = gridDim.y;
  const int L = blockIdx.y * gN + blockIdx.x;
  const int xcd = L & 7, j = L >> 3;
  const int Mq = gM >> 2, Nq = gN >> 1;
  tileM = (((xcd >> 1) * Mq) + j / Nq) * BMv;
  tileN = (((xcd & 1) * Nq) + j % Nq) * BNv;
}

// ------------------------------------------------ merged prep (1 launch)
// range 1: x fp32 -> xbf bf16 (8/thread); range 2: wq|wk|wv -> wcat;
// range 3: bq|bk|bv -> bcat fp32. Disjoint ranges, pure elementwise.
__global__ __launch_bounds__(256) void prep_kernel(
    const float* __restrict__ x, const float* __restrict__ wq,
    const float* __restrict__ wk, const float* __restrict__ wv,
    const float* __restrict__ bq, const float* __restrict__ bk,
    const float* __restrict__ bv, u16* __restrict__ xbf,
    u16* __restrict__ wcat, float* __restrict__ bcat) {
  const int NX = BB * TT * DD / 8;  // 1048576 x-units
  const int NW = DD * DD / 8;       // 131072 per-w units
  int i = blockIdx.x * 256 + threadIdx.x;
  if (i < NX) {
    const f32x4* p = (const f32x4*)x;
    f32x4 a = p[2 * (size_t)i];
    f32x4 b = p[2 * (size_t)i + 1];
    u16x8 o;
    o[0] = f2bf(a[0]); o[1] = f2bf(a[1]); o[2] = f2bf(a[2]); o[3] = f2bf(a[3]);
    o[4] = f2bf(b[0]); o[5] = f2bf(b[1]); o[6] = f2bf(b[2]); o[7] = f2bf(b[3]);
    *(u16x8*)(xbf + 8 * (size_t)i) = o;
  } else if (i < NX + 3 * NW) {
    const int k = i - NX;
    const float* src = k < NW ? wq : (k < 2 * NW ? wk : wv);
    const int ii = k < NW ? k : (k < 2 * NW ? k - NW : k - 2 * NW);
    const f32x4* p = (const f32x4*)src;
    f32x4 a = p[2 * (size_t)ii];
    f32x4 b = p[2 * (size_t)ii + 1];
    u16x8 o;
    o[0] = f2bf(a[0]); o[1] = f2bf(a[1]); o[2] = f2bf(a[2]); o[3] = f2bf(a[3]);
    o[4] = f2bf(b[0]); o[5] = f2bf(b[1]); o[6] = f2bf(b[2]); o[7] = f2bf(b[3]);
    *(u16x8*)(wcat + 8 * (size_t)k) = o;
  } else {
    const int k = i - NX - 3 * NW;
    if (k < 3 * DD) {
      float v = k < DD ? bq[k] : (k < 2 * DD ? bk[k - DD] : bv[k - 2 * DD]);
      bcat[k] = v;
    }
  }
}

// -------------------------------------------------- 128^2 K-loop (proven)
// 256 thr (4 waves), 2-barrier K-step via __syncthreads.
// Row = 64 elems = 8 x 16B chunks; global chunk c stored at LDS pos
// c^(r&7) (measured 0 bank conflicts). Used by gemm_qkv.
__device__ __forceinline__ void kloop_bt(
    const u16* __restrict__ A, const u16* __restrict__ B, int lda, int ldb,
    int K, int tileM, int tileN, u16* sA, u16* sB, f32x4 acc[4][4]) {
  const int tid = threadIdx.x;
  const int lane = tid & 63;
  const int wave = tid >> 6;
  const int quad = lane >> 4;
  const int l15 = lane & 15;
  const int wm = (wave >> 1) << 6;
  const int wn = (wave & 1) << 6;

  const u16 *gA[4], *gB[4];
  u16 *lA[4], *lB[4];
#pragma unroll
  for (int j = 0; j < 4; ++j) {
    const int ch = wave * 256 + j * 64 + lane;
    const int r = ch >> 3;
    const int cg = ((ch & 7) ^ (r & 7)) * 8;
    gA[j] = A + (size_t)(tileM + r) * lda + cg;
    gB[j] = B + (size_t)(tileN + r) * ldb + cg;
    lA[j] = sA + wave * 2048 + j * 512;
    lB[j] = sB + wave * 2048 + j * 512;
  }

  const int x0 = (quad ^ (l15 & 7)) * 8;
  int aOff[4], bOff[4];
#pragma unroll
  for (int i = 0; i < 4; ++i) {
    aOff[i] = (wm + i * 16 + l15) * 64 + x0;
    bOff[i] = (wn + i * 16 + l15) * 64 + x0;
  }

  for (int it = 0; it < K; it += 64) {
#pragma unroll
    for (int j = 0; j < 4; ++j) gload_lds16(gA[j], lA[j]);
#pragma unroll
    for (int j = 0; j < 4; ++j) gload_lds16(gB[j], lB[j]);
#pragma unroll
    for (int j = 0; j < 4; ++j) { gA[j] += 64; gB[j] += 64; }
    __syncthreads();

    s16x8 af[4], bf[4];
#pragma unroll
    for (int i = 0; i < 4; ++i) af[i] = *(const s16x8*)(sA + aOff[i]);
#pragma unroll
    for (int i = 0; i < 4; ++i) bf[i] = *(const s16x8*)(sB + bOff[i]);
#pragma unroll
    for (int mi = 0; mi < 4; ++mi)
#pragma unroll
      for (int ni = 0; ni < 4; ++ni)
        acc[mi][ni] = __builtin_amdgcn_mfma_f32_16x16x32_bf16(
            af[mi], bf[ni], acc[mi][ni], 0, 0, 0);

#pragma unroll
    for (int i = 0; i < 4; ++i) af[i] = *(const s16x8*)(sA + (aOff[i] ^ 32));
#pragma unroll
    for (int i = 0; i < 4; ++i) bf[i] = *(const s16x8*)(sB + (bOff[i] ^ 32));
#pragma unroll
    for (int mi = 0; mi < 4; ++mi)
#pragma unroll
      for (int ni = 0; ni < 4; ++ni)
        acc[mi][ni] = __builtin_amdgcn_mfma_f32_16x16x32_bf16(
            af[mi], bf[ni], acc[mi][ni], 0, 0, 0);
    __syncthreads();
  }
}

// -------------------------------------------------- 128^2 dbuf-counted
// (round-6 structure for gemm_s / gemm_pv — the best-measured config)
__device__ __forceinline__ void kloop_dbc(
    const u16* __restrict__ A, const u16* __restrict__ B, int lda, int ldb,
    int K, int tileM, int tileN, u16* sm, f32x4 acc[4][4]) {
  const int tid = threadIdx.x;
  const int lane = tid & 63;
  const int wave = tid >> 6;
  const int quad = lane >> 4;
  const int l15 = lane & 15;
  const int wm = (wave >> 1) << 6;
  const int wn = (wave & 1) << 6;

  const u16 *gA[4], *gB[4];
  int lA[4], lB[4];
#pragma unroll
  for (int j = 0; j < 4; ++j) {
    const int ch = wave * 256 + j * 64 + lane;
    const int r = ch >> 3;
    const int cg = ((ch & 7) ^ (r & 7)) * 8;
    gA[j] = A + (size_t)(tileM + r) * lda + cg;
    gB[j] = B + (size_t)(tileN + r) * ldb + cg;
    lA[j] = wave * 2048 + j * 512;
    lB[j] = 8192 + wave * 2048 + j * 512;
  }

  const int x0 = (quad ^ (l15 & 7)) * 8;
  int aOff[4], bOff[4];
#pragma unroll
  for (int i = 0; i < 4; ++i) {
    aOff[i] = (wm + i * 16 + l15) * 64 + x0;
    bOff[i] = 8192 + (wn + i * 16 + l15) * 64 + x0;
  }

  // prologue: stage tiles 0,1 into buf0,buf1 (16 loads/wave in flight)
#pragma unroll
  for (int p = 0; p < 2; ++p) {
    u16* d = sm + p * 16384;
#pragma unroll
    for (int j = 0; j < 4; ++j) gload_lds16(gA[j], d + lA[j]);
#pragma unroll
    for (int j = 0; j < 4; ++j) gload_lds16(gB[j], d + lB[j]);
#pragma unroll
    for (int j = 0; j < 4; ++j) { gA[j] += 64; gB[j] += 64; }
  }

  const int NT = K >> 6;
  for (int t = 0; t < NT; ++t) {
    const u16* sb = sm + (t & 1) * 16384;
    u16* st = sm + (t & 1) * 16384;  // t+2 reuses this buffer

    if (t + 1 < NT) {
      asm volatile("s_waitcnt vmcnt(8)" ::: "memory");  // tile t landed
    } else {
      asm volatile("s_waitcnt vmcnt(0)" ::: "memory");  // last tile
    }
    __builtin_amdgcn_s_barrier();  // collective: buf[t&1] complete
    __builtin_amdgcn_sched_barrier(0);

    s16x8 a0[4], b0[4], a1[4], b1[4];
#pragma unroll
    for (int i = 0; i < 4; ++i) a0[i] = *(const s16x8*)(sb + aOff[i]);
#pragma unroll
    for (int i = 0; i < 4; ++i) b0[i] = *(const s16x8*)(sb + bOff[i]);
#pragma unroll
    for (int i = 0; i < 4; ++i) a1[i] = *(const s16x8*)(sb + (aOff[i] ^ 32));
#pragma unroll
    for (int i = 0; i < 4; ++i) b1[i] = *(const s16x8*)(sb + (bOff[i] ^ 32));
    asm volatile("s_waitcnt lgkmcnt(0)" ::: "memory");
    __builtin_amdgcn_sched_barrier(0);
    __builtin_amdgcn_s_barrier();  // all waves done READING buf[t&1]
    __builtin_amdgcn_sched_barrier(0);

    if (t + 2 < NT) {  // overwrite freed buffer; loads fly under MFMA
#pragma unroll
      for (int j = 0; j < 4; ++j) gload_lds16(gA[j], st + lA[j]);
#pragma unroll
      for (int j = 0; j < 4; ++j) gload_lds16(gB[j], st + lB[j]);
#pragma unroll
      for (int j = 0; j < 4; ++j) { gA[j] += 64; gB[j] += 64; }
    }

    __builtin_amdgcn_s_setprio(1);
#pragma unroll
    for (int mi = 0; mi < 4; ++mi)
#pragma unroll
      for (int ni = 0; ni < 4; ++ni)
        acc[mi][ni] = __builtin_amdgcn_mfma_f32_16x16x32_bf16(
            a0[mi], b0[ni], acc[mi][ni], 0, 0, 0);
#pragma unroll
    for (int mi = 0; mi < 4; ++mi)
#pragma unroll
      for (int ni = 0; ni < 4; ++ni)
        acc[mi][ni] = __builtin_amdgcn_mfma_f32_16x16x32_bf16(
            a1[mi], b1[ni], acc[mi][ni], 0, 0, 0);
    __builtin_amdgcn_s_setprio(0);
  }
}

// -------------------------------------------------- fused QKV projection
// Round-0 proven structure; THIS ROUND'S ONLY CHANGE: launch_bounds
// min-waves 2 -> 4 (occupancy probe). Resources allow 4 blocks/CU
// (VGPR 72 <= 128 budget, LDS 32 KB x 4 <= 160 KB); counters have shown
// only ~8 waves/CU resident. If the bound was the cap, occupancy ~2x.
__global__ __launch_bounds__(256, 4) void gemm_qkv(
    const u16* __restrict__ A, const u16* __restrict__ B,
    u16* __restrict__ qk, u16* __restrict__ vt, const float* __restrict__ bias) {
  __shared__ u16 sA[128 * 64];
  __shared__ u16 sB[128 * 64];
  const int lane = threadIdx.x & 63;
  const int wave = threadIdx.x >> 6;
  const int quad = lane >> 4;
  const int l15 = lane & 15;
  const int wm = (wave >> 1) << 6;
  const int wn = (wave & 1) << 6;
  int tileM, tileN;
  swz(128, 128, tileM, tileN);

  f32x4 acc[4][4] = {};
  kloop_bt(A, B, DD, DD, DD, tileM, tileN, sA, sB, acc);

  const int rowB = tileM + wm + quad * 4;
  const int colB = tileN + wn + l15;
  if (tileN < 2048) {
    const float scale = (tileN < 1024) ? 0.03125f : 1.0f;  // 1/sqrt(1024)
#pragma unroll
    for (int mi = 0; mi < 4; ++mi)
#pragma unroll
      for (int r = 0; r < 4; ++r) {
        u16* crow = qk + (size_t)(rowB + mi * 16 + r) * 2048 + colB;
#pragma unroll
        for (int ni = 0; ni < 4; ++ni)
          crow[ni * 16] = f2bf((acc[mi][ni][r] + bias[colB + ni * 16]) * scale);
      }
  } else {
    const int b = tileM >> 11;
    const int tBase = (rowB & 2047);
    u16* vb = vt + (size_t)b * DD * TT;
#pragma unroll
    for (int mi = 0; mi < 4; ++mi)
#pragma unroll
      for (int ni = 0; ni < 4; ++ni) {
        const int e = colB + ni * 16 - 2048;
        const float bs = bias[colB + ni * 16];
        u16x4 o;
#pragma unroll
        for (int r = 0; r < 4; ++r) o[r] = f2bf(acc[mi][ni][r] + bs);
        *(u16x4*)(vb + (size_t)e * TT + tBase + mi * 16) = o;
      }
  }
}

// -------------------------------------------------- S-gemm + exp + partials
// 128^2 tiles + counted-vmcnt dbuf. grid (16,16,4) @ 2 blocks/CU.
// (64 KB LDS caps residency at 2 regardless -> keep (256,2).)
__global__ __launch_bounds__(256, 2) void gemm_s(
    const u16* __restrict__ qk, u16* __restrict__ sbuf,
    float* __restrict__ part) {
  __shared__ u16 sm[2 * 16384];  // 64 KB
  const int lane = threadIdx.x & 63;
  const int wave = threadIdx.x >> 6;
  const int quad = lane >> 4;
  const int l15 = lane & 15;
  const int wm = (wave >> 1) << 6;
  const int wn = (wave & 1) << 6;
  int tileM, tileN;
  swz(128, 128, tileM, tileN);
  const int z = blockIdx.z;

  const u16* A = qk + (size_t)z * TT * 2048;         // q cols [0,1024)
  const u16* B = qk + (size_t)z * TT * 2048 + 1024;  // k cols [1024,2048)

  f32x4 acc[4][4] = {};
  kloop_dbc(A, B, 2048, 2048, 1024, tileM, tileN, sm, acc);

  const int rowB = tileM + wm + quad * 4;
  const int colB = tileN + wn + l15;
  u16* C = sbuf + (size_t)z * TT * 2048;
  const int nIdx2 = (tileN + wn) >> 6;  // 0..31
  float* prow = part + ((size_t)z * 32 + nIdx2) * TT;
#pragma unroll
  for (int mi = 0; mi < 4; ++mi)
#pragma unroll
    for (int r = 0; r < 4; ++r) {
      const int row = rowB + mi * 16 + r;
      u16* crow = C + (size_t)row * 2048 + colB;
      float s = 0.f;
#pragma unroll
      for (int ni = 0; ni < 4; ++ni) {
        const u16 h = f2bf(__expf(acc[mi][ni][r]));
        crow[ni * 16] = h;
        s += bf2f(h);  // sum the ROUNDED values for consistent normalization
      }
#pragma unroll
      for (int m = 1; m <= 8; m <<= 1) s += __shfl_xor(s, m, 64);
      if (l15 == 0) prow[row] = s;
    }
}

// -------------------------------------------------- PV gemm + normalize
// 128^2 tiles + counted-vmcnt dbuf. grid (8,16,4) @ 2 blocks/CU.
__global__ __launch_bounds__(256, 2) void gemm_pv(
    const u16* __restrict__ sbuf, const u16* __restrict__ vt,
    float* __restrict__ out, const float* __restrict__ part) {
  __shared__ u16 sm[2 * 16384];  // 64 KB
  __shared__ float rowInv[128];
  const int tid = threadIdx.x;
  const int lane = tid & 63;
  const int wave = tid >> 6;
  const int quad = lane >> 4;
  const int l15 = lane & 15;
  const int wm = (wave >> 1) << 6;
  const int wn = (wave & 1) << 6;
  int tileM, tileN;
  swz(128, 128, tileM, tileN);
  const int z = blockIdx.z;

  if (tid < 128) {
    const float* pp = part + (size_t)z * 32 * TT + tileM + tid;
    float s = 0.f;
#pragma unroll
    for (int j = 0; j < 32; ++j) s += pp[j * TT];
    rowInv[tid] = 1.0f / s;
  }
  // Full drain before the counted-vmcnt pipeline: keeps the rowInv
  // loads out of the kloop's vmcnt ledger (ledger must start at 0).
  __syncthreads();

  const u16* A = sbuf + (size_t)z * TT * 2048;
  const u16* B = vt + (size_t)z * DD * TT;

  f32x4 acc[4][4] = {};
  kloop_dbc(A, B, 2048, TT, TT, tileM, tileN, sm, acc);

  const int rowB = tileM + wm + quad * 4;
  const int colB = tileN + wn + l15;
  float* C = out + (size_t)z * TT * DD;
#pragma unroll
  for (int mi = 0; mi < 4; ++mi)
#pragma unroll
    for (int r = 0; r < 4; ++r) {
      const int lrow = wm + quad * 4 + mi * 16 + r;
      const float inv = rowInv[lrow];
      float* crow = C + (size_t)(rowB + mi * 16 + r) * DD + colB;
#pragma unroll
      for (int ni = 0; ni < 4; ++ni) crow[ni * 16] = acc[mi][ni][r] * inv;
    }
}

// ---------------------------------------------------------------- launcher
extern "C" void kernel_launch(void* const* d_in, const int* in_sizes, int n_in,
                              void* d_out, int out_size, void* d_ws,
                              size_t ws_size, hipStream_t stream) {
  const float* x = (const float*)d_in[0];
  const float* wq = (const float*)d_in[1];
  const float* bq = (const float*)d_in[2];
  const float* wk = (const float*)d_in[3];
  const float* bk = (const float*)d_in[4];
  const float* wv = (const float*)d_in[5];
  const float* bv = (const float*)d_in[6];
  float* out = (float*)d_out;

  const size_t MB = 1024 * 1024;
  // Workspace layout (103 MB):
  //  [0,16)  xbf (dead after QKV) -- part [4][32][2048] fp32 (1MB) aliases
  //          its head: written by gemm_s AFTER QKV consumed xbf.
  //  [16,22) wcat   [22,+12K) bcat
  //  [23,55) qk [8192][2048] bf16   [55,71) vt [4][1024][2048] bf16
  //  [71,103) sbuf [4][2048][2048] bf16 (unnormalized P)
  if (ws_size < 103 * MB) return;
  char* ws = (char*)d_ws;
  u16* xbf = (u16*)(ws);
  float* part = (float*)(ws);  // aliases xbf head (safe: see ordering above)
  u16* wcat = (u16*)(ws + 16 * MB);
  float* bcat = (float*)(ws + 22 * MB);
  u16* qk = (u16*)(ws + 23 * MB);
  u16* vt = (u16*)(ws + 55 * MB);
  u16* sbuf = (u16*)(ws + 71 * MB);

  const dim3 blk256(256);

  // merged prep: x-cast (4096 blk) + w-cast (1536) + bias (12)
  prep_kernel<<<4096 + 1536 + 12, blk256, 0, stream>>>(
      x, wq, wk, wv, bq, bk, bv, xbf, wcat, bcat);

  // qkv: round-0 proven 128^2 -> 24x64 = 1536 blocks (occupancy probe @4)
  gemm_qkv<<<dim3(3 * DD / 128, BB * TT / 128, 1), blk256, 0, stream>>>(
      xbf, wcat, qk, vt, bcat);

  // s: 128^2 dbuf-counted -> (16,16,4) = 1024 blocks @ 2/CU
  gemm_s<<<dim3(TT / 128, TT / 128, BB), blk256, 0, stream>>>(qk, sbuf, part);

  // pv: 128^2 dbuf-counted -> (8,16,4) = 512 blocks @ 2/CU
  gemm_pv<<<dim3(DD / 128, TT / 128, BB), blk256, 0, stream>>>(
      sbuf, vt, out, part);
}

// Round 11
// 232.955 us; speedup vs baseline: 1.1815x; 1.1815x over previous
//
#include <hip/hip_runtime.h>
#include <stdint.h>

#define BB 4
#define TT 2048
#define DD 1024

typedef unsigned short u16;
typedef unsigned int u32;
typedef u16 u16x4 __attribute__((ext_vector_type(4)));
typedef u16 u16x8 __attribute__((ext_vector_type(8)));
typedef float f32x4 __attribute__((ext_vector_type(4)));
typedef short s16x8 __attribute__((ext_vector_type(8)));

__device__ __forceinline__ u16 f2bf(float f) {
  u32 u = __float_as_uint(f);
  return (u16)((u + 0x7fffu + ((u >> 16) & 1u)) >> 16);
}
__device__ __forceinline__ float bf2f(u16 h) {
  return __uint_as_float((u32)h << 16);
}

__device__ __forceinline__ void gload_lds16(const void* g, void* l) {
  __builtin_amdgcn_global_load_lds(
      (const __attribute__((address_space(1))) u32*)g,
      (__attribute__((address_space(3))) u32*)l, 16, 0, 0);
}

// XCD-aware block swizzle (bijection; needs gridM%4==0, gridN%2==0).
__device__ __forceinline__ void swz(int BMv, int BNv, int& tileM, int& tileN) {
  const int gN = gridDim.x, gM = gridDim.y;
  const int L = blockIdx.y * gN + blockIdx.x;
  const int xcd = L & 7, j = L >> 3;
  const int Mq = gM >> 2, Nq = gN >> 1;
  tileM = (((xcd >> 1) * Mq) + j / Nq) * BMv;
  tileN = (((xcd & 1) * Nq) + j % Nq) * BNv;
}

// ------------------------------------------------ merged prep (1 launch)
// range 1: x fp32 -> xbf bf16 (8/thread); range 2: wq|wk|wv -> wcat;
// range 3: bq|bk|bv -> bcat fp32. Disjoint ranges, pure elementwise.
__global__ __launch_bounds__(256) void prep_kernel(
    const float* __restrict__ x, const float* __restrict__ wq,
    const float* __restrict__ wk, const float* __restrict__ wv,
    const float* __restrict__ bq, const float* __restrict__ bk,
    const float* __restrict__ bv, u16* __restrict__ xbf,
    u16* __restrict__ wcat, float* __restrict__ bcat) {
  const int NX = BB * TT * DD / 8;  // 1048576 x-units
  const int NW = DD * DD / 8;       // 131072 per-w units
  int i = blockIdx.x * 256 + threadIdx.x;
  if (i < NX) {
    const f32x4* p = (const f32x4*)x;
    f32x4 a = p[2 * (size_t)i];
    f32x4 b = p[2 * (size_t)i + 1];
    u16x8 o;
    o[0] = f2bf(a[0]); o[1] = f2bf(a[1]); o[2] = f2bf(a[2]); o[3] = f2bf(a[3]);
    o[4] = f2bf(b[0]); o[5] = f2bf(b[1]); o[6] = f2bf(b[2]); o[7] = f2bf(b[3]);
    *(u16x8*)(xbf + 8 * (size_t)i) = o;
  } else if (i < NX + 3 * NW) {
    const int k = i - NX;
    const float* src = k < NW ? wq : (k < 2 * NW ? wk : wv);
    const int ii = k < NW ? k : (k < 2 * NW ? k - NW : k - 2 * NW);
    const f32x4* p = (const f32x4*)src;
    f32x4 a = p[2 * (size_t)ii];
    f32x4 b = p[2 * (size_t)ii + 1];
    u16x8 o;
    o[0] = f2bf(a[0]); o[1] = f2bf(a[1]); o[2] = f2bf(a[2]); o[3] = f2bf(a[3]);
    o[4] = f2bf(b[0]); o[5] = f2bf(b[1]); o[6] = f2bf(b[2]); o[7] = f2bf(b[3]);
    *(u16x8*)(wcat + 8 * (size_t)k) = o;
  } else {
    const int k = i - NX - 3 * NW;
    if (k < 3 * DD) {
      float v = k < DD ? bq[k] : (k < 2 * DD ? bk[k - DD] : bv[k - 2 * DD]);
      bcat[k] = v;
    }
  }
}

// -------------------------------------------------- 128^2 K-loop (proven)
// 256 thr (4 waves), 2-barrier K-step via __syncthreads.
// Row = 64 elems = 8 x 16B chunks; global chunk c stored at LDS pos
// c^(r&7) (measured 0 bank conflicts). Used by gemm_qkv.
__device__ __forceinline__ void kloop_bt(
    const u16* __restrict__ A, const u16* __restrict__ B, int lda, int ldb,
    int K, int tileM, int tileN, u16* sA, u16* sB, f32x4 acc[4][4]) {
  const int tid = threadIdx.x;
  const int lane = tid & 63;
  const int wave = tid >> 6;
  const int quad = lane >> 4;
  const int l15 = lane & 15;
  const int wm = (wave >> 1) << 6;
  const int wn = (wave & 1) << 6;

  const u16 *gA[4], *gB[4];
  u16 *lA[4], *lB[4];
#pragma unroll
  for (int j = 0; j < 4; ++j) {
    const int ch = wave * 256 + j * 64 + lane;
    const int r = ch >> 3;
    const int cg = ((ch & 7) ^ (r & 7)) * 8;
    gA[j] = A + (size_t)(tileM + r) * lda + cg;
    gB[j] = B + (size_t)(tileN + r) * ldb + cg;
    lA[j] = sA + wave * 2048 + j * 512;
    lB[j] = sB + wave * 2048 + j * 512;
  }

  const int x0 = (quad ^ (l15 & 7)) * 8;
  int aOff[4], bOff[4];
#pragma unroll
  for (int i = 0; i < 4; ++i) {
    aOff[i] = (wm + i * 16 + l15) * 64 + x0;
    bOff[i] = (wn + i * 16 + l15) * 64 + x0;
  }

  for (int it = 0; it < K; it += 64) {
#pragma unroll
    for (int j = 0; j < 4; ++j) gload_lds16(gA[j], lA[j]);
#pragma unroll
    for (int j = 0; j < 4; ++j) gload_lds16(gB[j], lB[j]);
#pragma unroll
    for (int j = 0; j < 4; ++j) { gA[j] += 64; gB[j] += 64; }
    __syncthreads();

    s16x8 af[4], bf[4];
#pragma unroll
    for (int i = 0; i < 4; ++i) af[i] = *(const s16x8*)(sA + aOff[i]);
#pragma unroll
    for (int i = 0; i < 4; ++i) bf[i] = *(const s16x8*)(sB + bOff[i]);
#pragma unroll
    for (int mi = 0; mi < 4; ++mi)
#pragma unroll
      for (int ni = 0; ni < 4; ++ni)
        acc[mi][ni] = __builtin_amdgcn_mfma_f32_16x16x32_bf16(
            af[mi], bf[ni], acc[mi][ni], 0, 0, 0);

#pragma unroll
    for (int i = 0; i < 4; ++i) af[i] = *(const s16x8*)(sA + (aOff[i] ^ 32));
#pragma unroll
    for (int i = 0; i < 4; ++i) bf[i] = *(const s16x8*)(sB + (bOff[i] ^ 32));
#pragma unroll
    for (int mi = 0; mi < 4; ++mi)
#pragma unroll
      for (int ni = 0; ni < 4; ++ni)
        acc[mi][ni] = __builtin_amdgcn_mfma_f32_16x16x32_bf16(
            af[mi], bf[ni], acc[mi][ni], 0, 0, 0);
    __syncthreads();
  }
}

// -------------------------------------------------- 128^2 dbuf-counted
// (round-6 structure for gemm_s / gemm_pv — the best-measured config)
__device__ __forceinline__ void kloop_dbc(
    const u16* __restrict__ A, const u16* __restrict__ B, int lda, int ldb,
    int K, int tileM, int tileN, u16* sm, f32x4 acc[4][4]) {
  const int tid = threadIdx.x;
  const int lane = tid & 63;
  const int wave = tid >> 6;
  const int quad = lane >> 4;
  const int l15 = lane & 15;
  const int wm = (wave >> 1) << 6;
  const int wn = (wave & 1) << 6;

  const u16 *gA[4], *gB[4];
  int lA[4], lB[4];
#pragma unroll
  for (int j = 0; j < 4; ++j) {
    const int ch = wave * 256 + j * 64 + lane;
    const int r = ch >> 3;
    const int cg = ((ch & 7) ^ (r & 7)) * 8;
    gA[j] = A + (size_t)(tileM + r) * lda + cg;
    gB[j] = B + (size_t)(tileN + r) * ldb + cg;
    lA[j] = wave * 2048 + j * 512;
    lB[j] = 8192 + wave * 2048 + j * 512;
  }

  const int x0 = (quad ^ (l15 & 7)) * 8;
  int aOff[4], bOff[4];
#pragma unroll
  for (int i = 0; i < 4; ++i) {
    aOff[i] = (wm + i * 16 + l15) * 64 + x0;
    bOff[i] = 8192 + (wn + i * 16 + l15) * 64 + x0;
  }

  // prologue: stage tiles 0,1 into buf0,buf1 (16 loads/wave in flight)
#pragma unroll
  for (int p = 0; p < 2; ++p) {
    u16* d = sm + p * 16384;
#pragma unroll
    for (int j = 0; j < 4; ++j) gload_lds16(gA[j], d + lA[j]);
#pragma unroll
    for (int j = 0; j < 4; ++j) gload_lds16(gB[j], d + lB[j]);
#pragma unroll
    for (int j = 0; j < 4; ++j) { gA[j] += 64; gB[j] += 64; }
  }

  const int NT = K >> 6;
  for (int t = 0; t < NT; ++t) {
    const u16* sb = sm + (t & 1) * 16384;
    u16* st = sm + (t & 1) * 16384;  // t+2 reuses this buffer

    if (t + 1 < NT) {
      asm volatile("s_waitcnt vmcnt(8)" ::: "memory");  // tile t landed
    } else {
      asm volatile("s_waitcnt vmcnt(0)" ::: "memory");  // last tile
    }
    __builtin_amdgcn_s_barrier();  // collective: buf[t&1] complete
    __builtin_amdgcn_sched_barrier(0);

    s16x8 a0[4], b0[4], a1[4], b1[4];
#pragma unroll
    for (int i = 0; i < 4; ++i) a0[i] = *(const s16x8*)(sb + aOff[i]);
#pragma unroll
    for (int i = 0; i < 4; ++i) b0[i] = *(const s16x8*)(sb + bOff[i]);
#pragma unroll
    for (int i = 0; i < 4; ++i) a1[i] = *(const s16x8*)(sb + (aOff[i] ^ 32));
#pragma unroll
    for (int i = 0; i < 4; ++i) b1[i] = *(const s16x8*)(sb + (bOff[i] ^ 32));
    asm volatile("s_waitcnt lgkmcnt(0)" ::: "memory");
    __builtin_amdgcn_sched_barrier(0);
    __builtin_amdgcn_s_barrier();  // all waves done READING buf[t&1]
    __builtin_amdgcn_sched_barrier(0);

    if (t + 2 < NT) {  // overwrite freed buffer; loads fly under MFMA
#pragma unroll
      for (int j = 0; j < 4; ++j) gload_lds16(gA[j], st + lA[j]);
#pragma unroll
      for (int j = 0; j < 4; ++j) gload_lds16(gB[j], st + lB[j]);
#pragma unroll
      for (int j = 0; j < 4; ++j) { gA[j] += 64; gB[j] += 64; }
    }

    __builtin_amdgcn_s_setprio(1);
#pragma unroll
    for (int mi = 0; mi < 4; ++mi)
#pragma unroll
      for (int ni = 0; ni < 4; ++ni)
        acc[mi][ni] = __builtin_amdgcn_mfma_f32_16x16x32_bf16(
            a0[mi], b0[ni], acc[mi][ni], 0, 0, 0);
#pragma unroll
    for (int mi = 0; mi < 4; ++mi)
#pragma unroll
      for (int ni = 0; ni < 4; ++ni)
        acc[mi][ni] = __builtin_amdgcn_mfma_f32_16x16x32_bf16(
            a1[mi], b1[ni], acc[mi][ni], 0, 0, 0);
    __builtin_amdgcn_s_setprio(0);
  }
}

// -------------------------------------------------- fused QKV projection
// Round-0 structure; round-11 probe: launch_bounds (256,3).
// R10 proved the attribute gates residency (occ 23->35% at min-waves=4)
// but 4 waves/SIMD caps regs at 128 < 136 needed -> spill (WRITE 203MB).
// 3 waves/SIMD budget = 170 regs >= 72 VGPR + 64 AGPR in use -> 3
// blocks/CU resident with NO spill. LDS 3x32KB=96<=160KB. Grid 1536 =
// 2 perfect passes at 768 blocks.
__global__ __launch_bounds__(256, 3) void gemm_qkv(
    const u16* __restrict__ A, const u16* __restrict__ B,
    u16* __restrict__ qk, u16* __restrict__ vt, const float* __restrict__ bias) {
  __shared__ u16 sA[128 * 64];
  __shared__ u16 sB[128 * 64];
  const int lane = threadIdx.x & 63;
  const int wave = threadIdx.x >> 6;
  const int quad = lane >> 4;
  const int l15 = lane & 15;
  const int wm = (wave >> 1) << 6;
  const int wn = (wave & 1) << 6;
  int tileM, tileN;
  swz(128, 128, tileM, tileN);

  f32x4 acc[4][4] = {};
  kloop_bt(A, B, DD, DD, DD, tileM, tileN, sA, sB, acc);

  const int rowB = tileM + wm + quad * 4;
  const int colB = tileN + wn + l15;
  if (tileN < 2048) {
    const float scale = (tileN < 1024) ? 0.03125f : 1.0f;  // 1/sqrt(1024)
#pragma unroll
    for (int mi = 0; mi < 4; ++mi)
#pragma unroll
      for (int r = 0; r < 4; ++r) {
        u16* crow = qk + (size_t)(rowB + mi * 16 + r) * 2048 + colB;
#pragma unroll
        for (int ni = 0; ni < 4; ++ni)
          crow[ni * 16] = f2bf((acc[mi][ni][r] + bias[colB + ni * 16]) * scale);
      }
  } else {
    const int b = tileM >> 11;
    const int tBase = (rowB & 2047);
    u16* vb = vt + (size_t)b * DD * TT;
#pragma unroll
    for (int mi = 0; mi < 4; ++mi)
#pragma unroll
      for (int ni = 0; ni < 4; ++ni) {
        const int e = colB + ni * 16 - 2048;
        const float bs = bias[colB + ni * 16];
        u16x4 o;
#pragma unroll
        for (int r = 0; r < 4; ++r) o[r] = f2bf(acc[mi][ni][r] + bs);
        *(u16x4*)(vb + (size_t)e * TT + tBase + mi * 16) = o;
      }
  }
}

// -------------------------------------------------- S-gemm + exp + partials
// 128^2 tiles + counted-vmcnt dbuf. grid (16,16,4) @ 2 blocks/CU.
// (dbc holds 16 live fragments + 64 AGPR acc -> (256,3) could spill; keep 2.)
__global__ __launch_bounds__(256, 2) void gemm_s(
    const u16* __restrict__ qk, u16* __restrict__ sbuf,
    float* __restrict__ part) {
  __shared__ u16 sm[2 * 16384];  // 64 KB
  const int lane = threadIdx.x & 63;
  const int wave = threadIdx.x >> 6;
  const int quad = lane >> 4;
  const int l15 = lane & 15;
  const int wm = (wave >> 1) << 6;
  const int wn = (wave & 1) << 6;
  int tileM, tileN;
  swz(128, 128, tileM, tileN);
  const int z = blockIdx.z;

  const u16* A = qk + (size_t)z * TT * 2048;         // q cols [0,1024)
  const u16* B = qk + (size_t)z * TT * 2048 + 1024;  // k cols [1024,2048)

  f32x4 acc[4][4] = {};
  kloop_dbc(A, B, 2048, 2048, 1024, tileM, tileN, sm, acc);

  const int rowB = tileM + wm + quad * 4;
  const int colB = tileN + wn + l15;
  u16* C = sbuf + (size_t)z * TT * 2048;
  const int nIdx2 = (tileN + wn) >> 6;  // 0..31
  float* prow = part + ((size_t)z * 32 + nIdx2) * TT;
#pragma unroll
  for (int mi = 0; mi < 4; ++mi)
#pragma unroll
    for (int r = 0; r < 4; ++r) {
      const int row = rowB + mi * 16 + r;
      u16* crow = C + (size_t)row * 2048 + colB;
      float s = 0.f;
#pragma unroll
      for (int ni = 0; ni < 4; ++ni) {
        const u16 h = f2bf(__expf(acc[mi][ni][r]));
        crow[ni * 16] = h;
        s += bf2f(h);  // sum the ROUNDED values for consistent normalization
      }
#pragma unroll
      for (int m = 1; m <= 8; m <<= 1) s += __shfl_xor(s, m, 64);
      if (l15 == 0) prow[row] = s;
    }
}

// -------------------------------------------------- PV gemm + normalize
// 128^2 tiles + counted-vmcnt dbuf. grid (8,16,4) @ 2 blocks/CU.
__global__ __launch_bounds__(256, 2) void gemm_pv(
    const u16* __restrict__ sbuf, const u16* __restrict__ vt,
    float* __restrict__ out, const float* __restrict__ part) {
  __shared__ u16 sm[2 * 16384];  // 64 KB
  __shared__ float rowInv[128];
  const int tid = threadIdx.x;
  const int lane = tid & 63;
  const int wave = tid >> 6;
  const int quad = lane >> 4;
  const int l15 = lane & 15;
  const int wm = (wave >> 1) << 6;
  const int wn = (wave & 1) << 6;
  int tileM, tileN;
  swz(128, 128, tileM, tileN);
  const int z = blockIdx.z;

  if (tid < 128) {
    const float* pp = part + (size_t)z * 32 * TT + tileM + tid;
    float s = 0.f;
#pragma unroll
    for (int j = 0; j < 32; ++j) s += pp[j * TT];
    rowInv[tid] = 1.0f / s;
  }
  // Full drain before the counted-vmcnt pipeline: keeps the rowInv
  // loads out of the kloop's vmcnt ledger (ledger must start at 0).
  __syncthreads();

  const u16* A = sbuf + (size_t)z * TT * 2048;
  const u16* B = vt + (size_t)z * DD * TT;

  f32x4 acc[4][4] = {};
  kloop_dbc(A, B, 2048, TT, TT, tileM, tileN, sm, acc);

  const int rowB = tileM + wm + quad * 4;
  const int colB = tileN + wn + l15;
  float* C = out + (size_t)z * TT * DD;
#pragma unroll
  for (int mi = 0; mi < 4; ++mi)
#pragma unroll
    for (int r = 0; r < 4; ++r) {
      const int lrow = wm + quad * 4 + mi * 16 + r;
      const float inv = rowInv[lrow];
      float* crow = C + (size_t)(rowB + mi * 16 + r) * DD + colB;
#pragma unroll
      for (int ni = 0; ni < 4; ++ni) crow[ni * 16] = acc[mi][ni][r] * inv;
    }
}

// ---------------------------------------------------------------- launcher
extern "C" void kernel_launch(void* const* d_in, const int* in_sizes, int n_in,
                              void* d_out, int out_size, void* d_ws,
                              size_t ws_size, hipStream_t stream) {
  const float* x = (const float*)d_in[0];
  const float* wq = (const float*)d_in[1];
  const float* bq = (const float*)d_in[2];
  const float* wk = (const float*)d_in[3];
  const float* bk = (const float*)d_in[4];
  const float* wv = (const float*)d_in[5];
  const float* bv = (const float*)d_in[6];
  float* out = (float*)d_out;

  const size_t MB = 1024 * 1024;
  // Workspace layout (103 MB):
  //  [0,16)  xbf (dead after QKV) -- part [4][32][2048] fp32 (1MB) aliases
  //          its head: written by gemm_s AFTER QKV consumed xbf.
  //  [16,22) wcat   [22,+12K) bcat
  //  [23,55) qk [8192][2048] bf16   [55,71) vt [4][1024][2048] bf16
  //  [71,103) sbuf [4][2048][2048] bf16 (unnormalized P)
  if (ws_size < 103 * MB) return;
  char* ws = (char*)d_ws;
  u16* xbf = (u16*)(ws);
  float* part = (float*)(ws);  // aliases xbf head (safe: see ordering above)
  u16* wcat = (u16*)(ws + 16 * MB);
  float* bcat = (float*)(ws + 22 * MB);
  u16* qk = (u16*)(ws + 23 * MB);
  u16* vt = (u16*)(ws + 55 * MB);
  u16* sbuf = (u16*)(ws + 71 * MB);

  const dim3 blk256(256);

  // merged prep: x-cast (4096 blk) + w-cast (1536) + bias (12)
  prep_kernel<<<4096 + 1536 + 12, blk256, 0, stream>>>(
      x, wq, wk, wv, bq, bk, bv, xbf, wcat, bcat);

  // qkv: round-0 proven 128^2 -> 24x64 = 1536 blocks (3 blocks/CU probe)
  gemm_qkv<<<dim3(3 * DD / 128, BB * TT / 128, 1), blk256, 0, stream>>>(
      xbf, wcat, qk, vt, bcat);

  // s: 128^2 dbuf-counted -> (16,16,4) = 1024 blocks @ 2/CU
  gemm_s<<<dim3(TT / 128, TT / 128, BB), blk256, 0, stream>>>(qk, sbuf, part);

  // pv: 128^2 dbuf-counted -> (8,16,4) = 512 blocks @ 2/CU
  gemm_pv<<<dim3(DD / 128, TT / 128, BB), blk256, 0, stream>>>(
      sbuf, vt, out, part);
}

// Round 13
// 225.472 us; speedup vs baseline: 1.2207x; 1.0332x over previous
//
#include <hip/hip_runtime.h>
#include <stdint.h>

#define BB 4
#define TT 2048
#define DD 1024

typedef unsigned short u16;
typedef unsigned int u32;
typedef u16 u16x4 __attribute__((ext_vector_type(4)));
typedef u16 u16x8 __attribute__((ext_vector_type(8)));
typedef float f32x4 __attribute__((ext_vector_type(4)));
typedef short s16x8 __attribute__((ext_vector_type(8)));

__device__ __forceinline__ u16 f2bf(float f) {
  u32 u = __float_as_uint(f);
  return (u16)((u + 0x7fffu + ((u >> 16) & 1u)) >> 16);
}
__device__ __forceinline__ float bf2f(u16 h) {
  return __uint_as_float((u32)h << 16);
}

__device__ __forceinline__ void gload_lds16(const void* g, void* l) {
  __builtin_amdgcn_global_load_lds(
      (const __attribute__((address_space(1))) u32*)g,
      (__attribute__((address_space(3))) u32*)l, 16, 0, 0);
}

// XCD-aware block swizzle (bijection; needs gridM%4==0, gridN%2==0).
__device__ __forceinline__ void swz(int BMv, int BNv, int& tileM, int& tileN) {
  const int gN = gridDim.x, gM = gridDim.y;
  const int L = blockIdx.y * gN + blockIdx.x;
  const int xcd = L & 7, j = L >> 3;
  const int Mq = gM >> 2, Nq = gN >> 1;
  tileM = (((xcd >> 1) * Mq) + j / Nq) * BMv;
  tileN = (((xcd & 1) * Nq) + j % Nq) * BNv;
}

// ------------------------------------------------ merged prep (1 launch)
// range 1: x fp32 -> xbf bf16 (8/thread); range 2: wq|wk|wv -> wcat;
// range 3: bq|bk|bv -> bcat fp32. Disjoint ranges, pure elementwise.
__global__ __launch_bounds__(256) void prep_kernel(
    const float* __restrict__ x, const float* __restrict__ wq,
    const float* __restrict__ wk, const float* __restrict__ wv,
    const float* __restrict__ bq, const float* __restrict__ bk,
    const float* __restrict__ bv, u16* __restrict__ xbf,
    u16* __restrict__ wcat, float* __restrict__ bcat) {
  const int NX = BB * TT * DD / 8;  // 1048576 x-units
  const int NW = DD * DD / 8;       // 131072 per-w units
  int i = blockIdx.x * 256 + threadIdx.x;
  if (i < NX) {
    const f32x4* p = (const f32x4*)x;
    f32x4 a = p[2 * (size_t)i];
    f32x4 b = p[2 * (size_t)i + 1];
    u16x8 o;
    o[0] = f2bf(a[0]); o[1] = f2bf(a[1]); o[2] = f2bf(a[2]); o[3] = f2bf(a[3]);
    o[4] = f2bf(b[0]); o[5] = f2bf(b[1]); o[6] = f2bf(b[2]); o[7] = f2bf(b[3]);
    *(u16x8*)(xbf + 8 * (size_t)i) = o;
  } else if (i < NX + 3 * NW) {
    const int k = i - NX;
    const float* src = k < NW ? wq : (k < 2 * NW ? wk : wv);
    const int ii = k < NW ? k : (k < 2 * NW ? k - NW : k - 2 * NW);
    const f32x4* p = (const f32x4*)src;
    f32x4 a = p[2 * (size_t)ii];
    f32x4 b = p[2 * (size_t)ii + 1];
    u16x8 o;
    o[0] = f2bf(a[0]); o[1] = f2bf(a[1]); o[2] = f2bf(a[2]); o[3] = f2bf(a[3]);
    o[4] = f2bf(b[0]); o[5] = f2bf(b[1]); o[6] = f2bf(b[2]); o[7] = f2bf(b[3]);
    *(u16x8*)(wcat + 8 * (size_t)k) = o;
  } else {
    const int k = i - NX - 3 * NW;
    if (k < 3 * DD) {
      float v = k < DD ? bq[k] : (k < 2 * DD ? bk[k - DD] : bv[k - 2 * DD]);
      bcat[k] = v;
    }
  }
}

// -------------------------------------------------- 128^2 K-loop (proven)
// 256 thr (4 waves), 2 blocks/CU (measured optimum: R10 @4 spills,
// R11 @3 contends), 2-barrier K-step via __syncthreads.
// Row = 64 elems = 8 x 16B chunks; global chunk c stored at LDS pos
// c^(r&7) (measured 0 bank conflicts). Used by gemm_qkv.
__device__ __forceinline__ void kloop_bt(
    const u16* __restrict__ A, const u16* __restrict__ B, int lda, int ldb,
    int K, int tileM, int tileN, u16* sA, u16* sB, f32x4 acc[4][4]) {
  const int tid = threadIdx.x;
  const int lane = tid & 63;
  const int wave = tid >> 6;
  const int quad = lane >> 4;
  const int l15 = lane & 15;
  const int wm = (wave >> 1) << 6;
  const int wn = (wave & 1) << 6;

  const u16 *gA[4], *gB[4];
  u16 *lA[4], *lB[4];
#pragma unroll
  for (int j = 0; j < 4; ++j) {
    const int ch = wave * 256 + j * 64 + lane;
    const int r = ch >> 3;
    const int cg = ((ch & 7) ^ (r & 7)) * 8;
    gA[j] = A + (size_t)(tileM + r) * lda + cg;
    gB[j] = B + (size_t)(tileN + r) * ldb + cg;
    lA[j] = sA + wave * 2048 + j * 512;
    lB[j] = sB + wave * 2048 + j * 512;
  }

  const int x0 = (quad ^ (l15 & 7)) * 8;
  int aOff[4], bOff[4];
#pragma unroll
  for (int i = 0; i < 4; ++i) {
    aOff[i] = (wm + i * 16 + l15) * 64 + x0;
    bOff[i] = (wn + i * 16 + l15) * 64 + x0;
  }

  for (int it = 0; it < K; it += 64) {
#pragma unroll
    for (int j = 0; j < 4; ++j) gload_lds16(gA[j], lA[j]);
#pragma unroll
    for (int j = 0; j < 4; ++j) gload_lds16(gB[j], lB[j]);
#pragma unroll
    for (int j = 0; j < 4; ++j) { gA[j] += 64; gB[j] += 64; }
    __syncthreads();

    s16x8 af[4], bf[4];
#pragma unroll
    for (int i = 0; i < 4; ++i) af[i] = *(const s16x8*)(sA + aOff[i]);
#pragma unroll
    for (int i = 0; i < 4; ++i) bf[i] = *(const s16x8*)(sB + bOff[i]);
#pragma unroll
    for (int mi = 0; mi < 4; ++mi)
#pragma unroll
      for (int ni = 0; ni < 4; ++ni)
        acc[mi][ni] = __builtin_amdgcn_mfma_f32_16x16x32_bf16(
            af[mi], bf[ni], acc[mi][ni], 0, 0, 0);

#pragma unroll
    for (int i = 0; i < 4; ++i) af[i] = *(const s16x8*)(sA + (aOff[i] ^ 32));
#pragma unroll
    for (int i = 0; i < 4; ++i) bf[i] = *(const s16x8*)(sB + (bOff[i] ^ 32));
#pragma unroll
    for (int mi = 0; mi < 4; ++mi)
#pragma unroll
      for (int ni = 0; ni < 4; ++ni)
        acc[mi][ni] = __builtin_amdgcn_mfma_f32_16x16x32_bf16(
            af[mi], bf[ni], acc[mi][ni], 0, 0, 0);
    __syncthreads();
  }
}

// -------------------------------------------------- 128^2 dbuf-counted
// (round-6 structure for gemm_s / gemm_pv — the best-measured config)
__device__ __forceinline__ void kloop_dbc(
    const u16* __restrict__ A, const u16* __restrict__ B, int lda, int ldb,
    int K, int tileM, int tileN, u16* sm, f32x4 acc[4][4]) {
  const int tid = threadIdx.x;
  const int lane = tid & 63;
  const int wave = tid >> 6;
  const int quad = lane >> 4;
  const int l15 = lane & 15;
  const int wm = (wave >> 1) << 6;
  const int wn = (wave & 1) << 6;

  const u16 *gA[4], *gB[4];
  int lA[4], lB[4];
#pragma unroll
  for (int j = 0; j < 4; ++j) {
    const int ch = wave * 256 + j * 64 + lane;
    const int r = ch >> 3;
    const int cg = ((ch & 7) ^ (r & 7)) * 8;
    gA[j] = A + (size_t)(tileM + r) * lda + cg;
    gB[j] = B + (size_t)(tileN + r) * ldb + cg;
    lA[j] = wave * 2048 + j * 512;
    lB[j] = 8192 + wave * 2048 + j * 512;
  }

  const int x0 = (quad ^ (l15 & 7)) * 8;
  int aOff[4], bOff[4];
#pragma unroll
  for (int i = 0; i < 4; ++i) {
    aOff[i] = (wm + i * 16 + l15) * 64 + x0;
    bOff[i] = 8192 + (wn + i * 16 + l15) * 64 + x0;
  }

  // prologue: stage tiles 0,1 into buf0,buf1 (16 loads/wave in flight)
#pragma unroll
  for (int p = 0; p < 2; ++p) {
    u16* d = sm + p * 16384;
#pragma unroll
    for (int j = 0; j < 4; ++j) gload_lds16(gA[j], d + lA[j]);
#pragma unroll
    for (int j = 0; j < 4; ++j) gload_lds16(gB[j], d + lB[j]);
#pragma unroll
    for (int j = 0; j < 4; ++j) { gA[j] += 64; gB[j] += 64; }
  }

  const int NT = K >> 6;
  for (int t = 0; t < NT; ++t) {
    const u16* sb = sm + (t & 1) * 16384;
    u16* st = sm + (t & 1) * 16384;  // t+2 reuses this buffer

    if (t + 1 < NT) {
      asm volatile("s_waitcnt vmcnt(8)" ::: "memory");  // tile t landed
    } else {
      asm volatile("s_waitcnt vmcnt(0)" ::: "memory");  // last tile
    }
    __builtin_amdgcn_s_barrier();  // collective: buf[t&1] complete
    __builtin_amdgcn_sched_barrier(0);

    s16x8 a0[4], b0[4], a1[4], b1[4];
#pragma unroll
    for (int i = 0; i < 4; ++i) a0[i] = *(const s16x8*)(sb + aOff[i]);
#pragma unroll
    for (int i = 0; i < 4; ++i) b0[i] = *(const s16x8*)(sb + bOff[i]);
#pragma unroll
    for (int i = 0; i < 4; ++i) a1[i] = *(const s16x8*)(sb + (aOff[i] ^ 32));
#pragma unroll
    for (int i = 0; i < 4; ++i) b1[i] = *(const s16x8*)(sb + (bOff[i] ^ 32));
    asm volatile("s_waitcnt lgkmcnt(0)" ::: "memory");
    __builtin_amdgcn_sched_barrier(0);
    __builtin_amdgcn_s_barrier();  // all waves done READING buf[t&1]
    __builtin_amdgcn_sched_barrier(0);

    if (t + 2 < NT) {  // overwrite freed buffer; loads fly under MFMA
#pragma unroll
      for (int j = 0; j < 4; ++j) gload_lds16(gA[j], st + lA[j]);
#pragma unroll
      for (int j = 0; j < 4; ++j) gload_lds16(gB[j], st + lB[j]);
#pragma unroll
      for (int j = 0; j < 4; ++j) { gA[j] += 64; gB[j] += 64; }
    }

    __builtin_amdgcn_s_setprio(1);
#pragma unroll
    for (int mi = 0; mi < 4; ++mi)
#pragma unroll
      for (int ni = 0; ni < 4; ++ni)
        acc[mi][ni] = __builtin_amdgcn_mfma_f32_16x16x32_bf16(
            a0[mi], b0[ni], acc[mi][ni], 0, 0, 0);
#pragma unroll
    for (int mi = 0; mi < 4; ++mi)
#pragma unroll
      for (int ni = 0; ni < 4; ++ni)
        acc[mi][ni] = __builtin_amdgcn_mfma_f32_16x16x32_bf16(
            a1[mi], b1[ni], acc[mi][ni], 0, 0, 0);
    __builtin_amdgcn_s_setprio(0);
  }
}

// -------------------------------------------------- fused QKV projection
// ROUND-0/6 PROVEN VERSION (61.2 +/- 0.3 us, 35% MfmaUtil, 49 MB writes).
// launch_bounds (256,2): measured optimum — (256,3) contends (+2.4 us),
// (256,4) spills (+41 us).
__global__ __launch_bounds__(256, 2) void gemm_qkv(
    const u16* __restrict__ A, const u16* __restrict__ B,
    u16* __restrict__ qk, u16* __restrict__ vt, const float* __restrict__ bias) {
  __shared__ u16 sA[128 * 64];
  __shared__ u16 sB[128 * 64];
  const int lane = threadIdx.x & 63;
  const int wave = threadIdx.x >> 6;
  const int quad = lane >> 4;
  const int l15 = lane & 15;
  const int wm = (wave >> 1) << 6;
  const int wn = (wave & 1) << 6;
  int tileM, tileN;
  swz(128, 128, tileM, tileN);

  f32x4 acc[4][4] = {};
  kloop_bt(A, B, DD, DD, DD, tileM, tileN, sA, sB, acc);

  const int rowB = tileM + wm + quad * 4;
  const int colB = tileN + wn + l15;
  if (tileN < 2048) {
    const float scale = (tileN < 1024) ? 0.03125f : 1.0f;  // 1/sqrt(1024)
#pragma unroll
    for (int mi = 0; mi < 4; ++mi)
#pragma unroll
      for (int r = 0; r < 4; ++r) {
        u16* crow = qk + (size_t)(rowB + mi * 16 + r) * 2048 + colB;
#pragma unroll
        for (int ni = 0; ni < 4; ++ni)
          crow[ni * 16] = f2bf((acc[mi][ni][r] + bias[colB + ni * 16]) * scale);
      }
  } else {
    const int b = tileM >> 11;
    const int tBase = (rowB & 2047);
    u16* vb = vt + (size_t)b * DD * TT;
#pragma unroll
    for (int mi = 0; mi < 4; ++mi)
#pragma unroll
      for (int ni = 0; ni < 4; ++ni) {
        const int e = colB + ni * 16 - 2048;
        const float bs = bias[colB + ni * 16];
        u16x4 o;
#pragma unroll
        for (int r = 0; r < 4; ++r) o[r] = f2bf(acc[mi][ni][r] + bs);
        *(u16x4*)(vb + (size_t)e * TT + tBase + mi * 16) = o;
      }
  }
}

// -------------------------------------------------- S-gemm + exp + partials
// 128^2 tiles + counted-vmcnt dbuf. grid (16,16,4) @ 2 blocks/CU.
__global__ __launch_bounds__(256, 2) void gemm_s(
    const u16* __restrict__ qk, u16* __restrict__ sbuf,
    float* __restrict__ part) {
  __shared__ u16 sm[2 * 16384];  // 64 KB
  const int lane = threadIdx.x & 63;
  const int wave = threadIdx.x >> 6;
  const int quad = lane >> 4;
  const int l15 = lane & 15;
  const int wm = (wave >> 1) << 6;
  const int wn = (wave & 1) << 6;
  int tileM, tileN;
  swz(128, 128, tileM, tileN);
  const int z = blockIdx.z;

  const u16* A = qk + (size_t)z * TT * 2048;         // q cols [0,1024)
  const u16* B = qk + (size_t)z * TT * 2048 + 1024;  // k cols [1024,2048)

  f32x4 acc[4][4] = {};
  kloop_dbc(A, B, 2048, 2048, 1024, tileM, tileN, sm, acc);

  const int rowB = tileM + wm + quad * 4;
  const int colB = tileN + wn + l15;
  u16* C = sbuf + (size_t)z * TT * 2048;
  const int nIdx2 = (tileN + wn) >> 6;  // 0..31
  float* prow = part + ((size_t)z * 32 + nIdx2) * TT;
#pragma unroll
  for (int mi = 0; mi < 4; ++mi)
#pragma unroll
    for (int r = 0; r < 4; ++r) {
      const int row = rowB + mi * 16 + r;
      u16* crow = C + (size_t)row * 2048 + colB;
      float s = 0.f;
#pragma unroll
      for (int ni = 0; ni < 4; ++ni) {
        const u16 h = f2bf(__expf(acc[mi][ni][r]));
        crow[ni * 16] = h;
        s += bf2f(h);  // sum the ROUNDED values for consistent normalization
      }
#pragma unroll
      for (int m = 1; m <= 8; m <<= 1) s += __shfl_xor(s, m, 64);
      if (l15 == 0) prow[row] = s;
    }
}

// -------------------------------------------------- PV gemm + normalize
// 128^2 tiles + counted-vmcnt dbuf. grid (8,16,4) @ 2 blocks/CU.
__global__ __launch_bounds__(256, 2) void gemm_pv(
    const u16* __restrict__ sbuf, const u16* __restrict__ vt,
    float* __restrict__ out, const float* __restrict__ part) {
  __shared__ u16 sm[2 * 16384];  // 64 KB
  __shared__ float rowInv[128];
  const int tid = threadIdx.x;
  const int lane = tid & 63;
  const int wave = tid >> 6;
  const int quad = lane >> 4;
  const int l15 = lane & 15;
  const int wm = (wave >> 1) << 6;
  const int wn = (wave & 1) << 6;
  int tileM, tileN;
  swz(128, 128, tileM, tileN);
  const int z = blockIdx.z;

  if (tid < 128) {
    const float* pp = part + (size_t)z * 32 * TT + tileM + tid;
    float s = 0.f;
#pragma unroll
    for (int j = 0; j < 32; ++j) s += pp[j * TT];
    rowInv[tid] = 1.0f / s;
  }
  // Full drain before the counted-vmcnt pipeline: keeps the rowInv
  // loads out of the kloop's vmcnt ledger (ledger must start at 0).
  __syncthreads();

  const u16* A = sbuf + (size_t)z * TT * 2048;
  const u16* B = vt + (size_t)z * DD * TT;

  f32x4 acc[4][4] = {};
  kloop_dbc(A, B, 2048, TT, TT, tileM, tileN, sm, acc);

  const int rowB = tileM + wm + quad * 4;
  const int colB = tileN + wn + l15;
  float* C = out + (size_t)z * TT * DD;
#pragma unroll
  for (int mi = 0; mi < 4; ++mi)
#pragma unroll
    for (int r = 0; r < 4; ++r) {
      const int lrow = wm + quad * 4 + mi * 16 + r;
      const float inv = rowInv[lrow];
      float* crow = C + (size_t)(rowB + mi * 16 + r) * DD + colB;
#pragma unroll
      for (int ni = 0; ni < 4; ++ni) crow[ni * 16] = acc[mi][ni][r] * inv;
    }
}

// ---------------------------------------------------------------- launcher
extern "C" void kernel_launch(void* const* d_in, const int* in_sizes, int n_in,
                              void* d_out, int out_size, void* d_ws,
                              size_t ws_size, hipStream_t stream) {
  const float* x = (const float*)d_in[0];
  const float* wq = (const float*)d_in[1];
  const float* bq = (const float*)d_in[2];
  const float* wk = (const float*)d_in[3];
  const float* bk = (const float*)d_in[4];
  const float* wv = (const float*)d_in[5];
  const float* bv = (const float*)d_in[6];
  float* out = (float*)d_out;

  const size_t MB = 1024 * 1024;
  // Workspace layout (103 MB):
  //  [0,16)  xbf (dead after QKV) -- part [4][32][2048] fp32 (1MB) aliases
  //          its head: written by gemm_s AFTER QKV consumed xbf.
  //  [16,22) wcat   [22,+12K) bcat
  //  [23,55) qk [8192][2048] bf16   [55,71) vt [4][1024][2048] bf16
  //  [71,103) sbuf [4][2048][2048] bf16 (unnormalized P)
  if (ws_size < 103 * MB) return;
  char* ws = (char*)d_ws;
  u16* xbf = (u16*)(ws);
  float* part = (float*)(ws);  // aliases xbf head (safe: see ordering above)
  u16* wcat = (u16*)(ws + 16 * MB);
  float* bcat = (float*)(ws + 22 * MB);
  u16* qk = (u16*)(ws + 23 * MB);
  u16* vt = (u16*)(ws + 55 * MB);
  u16* sbuf = (u16*)(ws + 71 * MB);

  const dim3 blk256(256);

  // merged prep: x-cast (4096 blk) + w-cast (1536) + bias (12)
  prep_kernel<<<4096 + 1536 + 12, blk256, 0, stream>>>(
      x, wq, wk, wv, bq, bk, bv, xbf, wcat, bcat);

  // qkv: round-0 proven 128^2 -> 24x64 = 1536 blocks @ 2/CU
  gemm_qkv<<<dim3(3 * DD / 128, BB * TT / 128, 1), blk256, 0, stream>>>(
      xbf, wcat, qk, vt, bcat);

  // s: 128^2 dbuf-counted -> (16,16,4) = 1024 blocks @ 2/CU
  gemm_s<<<dim3(TT / 128, TT / 128, BB), blk256, 0, stream>>>(qk, sbuf, part);

  // pv: 128^2 dbuf-counted -> (8,16,4) = 512 blocks @ 2/CU
  gemm_pv<<<dim3(DD / 128, TT / 128, BB), blk256, 0, stream>>>(
      sbuf, vt, out, part);
}